// Round 2
// baseline (457.513 us; speedup 1.0000x reference)
//
#include <hip/hip_runtime.h>
#include <stdint.h>

// Problem constants (from setup_inputs): B=4, L=4, N=2048, H=64, V=4

typedef __attribute__((ext_vector_type(4))) float  f32x4;
typedef __attribute__((ext_vector_type(8))) short  short8;

static __device__ __forceinline__ uint16_t f2bf(float f) {
    uint32_t u = __float_as_uint(f);
    u += 0x7FFFu + ((u >> 16) & 1u);   // round-to-nearest-even (finite inputs only)
    return (uint16_t)(u >> 16);
}

// ---------------------------------------------------------------------------
// Kernel 1: fused fc + LayerNorm + tanh + projection through M = a@W.
// Writes base = x + 0.2*(h@M0) to d_out (fp32) and zT[b][l][e][m] (bf16,
// B-fragment layout) for l=1..4 to d_ws.
// ---------------------------------------------------------------------------
__global__ __launch_bounds__(256) void prep_kernel(
    const float* __restrict__ x, const float* __restrict__ feat,
    const float* __restrict__ fc_w, const float* __restrict__ fc_b,
    const float* __restrict__ ln_g, const float* __restrict__ ln_b,
    const float* __restrict__ W, const float* __restrict__ a,
    float* __restrict__ out, uint16_t* __restrict__ zT)
{
    __shared__ float    sW[64 * 67];        // fc_w staged, pad 66->67
    __shared__ uint16_t sM[5 * 64 * 64];    // M[l][d][e] in bf16 (40 KB)

    const int tid = threadIdx.x;

    for (int i = tid; i < 64 * 66; i += 256) {
        int d = i / 66, k = i - d * 66;
        sW[d * 67 + k] = fc_w[i];
    }
    for (int i = tid; i < 5 * 64 * 64; i += 256) {
        int l = i >> 12;
        int d = (i >> 6) & 63;
        int e = i & 63;
        const float* wp = W + (size_t)(d * 4) * 64 + e;
        float acc = a[l * 4 + 0] * wp[0]   + a[l * 4 + 1] * wp[64]
                  + a[l * 4 + 2] * wp[128] + a[l * 4 + 3] * wp[192];
        sM[i] = f2bf(acc);
    }
    __syncthreads();

    const int wave = tid >> 6, lane = tid & 63;
    const int row0 = blockIdx.x * 32 + wave * 8;   // global row in [0, 8192)
    const int b    = row0 >> 11;
    const int m0   = row0 & 2047;

    const float fcb = fc_b[lane], lng = ln_g[lane], lnb = ln_b[lane];

    float xv[8], hv[8];
#pragma unroll
    for (int r = 0; r < 8; r++) {
        const int row = row0 + r;
        xv[r] = x[(size_t)row * 64 + lane];
        const float f0 = feat[row * 2 + 0];
        const float f1 = feat[row * 2 + 1];
        float acc = fcb;
#pragma unroll
        for (int k = 0; k < 64; k++)
            acc += __shfl(xv[r], k) * sW[lane * 67 + k];
        acc += f0 * sW[lane * 67 + 64] + f1 * sW[lane * 67 + 65];
        float s = acc, s2 = acc * acc;
#pragma unroll
        for (int off = 32; off > 0; off >>= 1) {
            s  += __shfl_xor(s,  off);
            s2 += __shfl_xor(s2, off);
        }
        const float mean = s * (1.0f / 64.0f);
        const float var  = s2 * (1.0f / 64.0f) - mean * mean;
        const float y = (acc - mean) * rsqrtf(var + 1e-5f) * lng + lnb;
        hv[r] = tanhf(y);
    }

    float accz[5][8];
#pragma unroll
    for (int l = 0; l < 5; l++)
#pragma unroll
        for (int r = 0; r < 8; r++) accz[l][r] = 0.0f;

    for (int d = 0; d < 64; d++) {
        float hb[8];
#pragma unroll
        for (int r = 0; r < 8; r++) hb[r] = __shfl(hv[r], d);
#pragma unroll
        for (int l = 0; l < 5; l++) {
            const float mv =
                __uint_as_float(((uint32_t)sM[(l << 12) + (d << 6) + lane]) << 16);
#pragma unroll
            for (int r = 0; r < 8; r++) accz[l][r] += hb[r] * mv;
        }
    }

#pragma unroll
    for (int r = 0; r < 8; r++)
        out[(size_t)(row0 + r) * 64 + lane] = xv[r] + 0.2f * accz[0][r];

#pragma unroll
    for (int l = 1; l < 5; l++) {
        uint32_t w0 = (uint32_t)f2bf(accz[l][0]) | ((uint32_t)f2bf(accz[l][1]) << 16);
        uint32_t w1 = (uint32_t)f2bf(accz[l][2]) | ((uint32_t)f2bf(accz[l][3]) << 16);
        uint32_t w2 = (uint32_t)f2bf(accz[l][4]) | ((uint32_t)f2bf(accz[l][5]) << 16);
        uint32_t w3 = (uint32_t)f2bf(accz[l][6]) | ((uint32_t)f2bf(accz[l][7]) << 16);
        uint4* dst = (uint4*)(zT + (((size_t)(b * 4 + (l - 1)) * 64 + lane) * 2048 + m0));
        *dst = make_uint4(w0, w1, w2, w3);
    }
}

// ---------------------------------------------------------------------------
// Kernel 2: out[b,n,e] = base[b,n,e] + 0.2 * sum_l sum_m adj[b,l,n,m]*z[l][m][e]
// One block (4 waves) owns a (b, 16-row) tile. Wave w handles label l=w over
// the FULL K=2048, then a 4-way LDS reduction and a single float4 RMW store.
// Zero atomics. Grid: 4(b) * 128(row-tile) = 512 blocks x 256 threads.
// ---------------------------------------------------------------------------
__global__ __launch_bounds__(256) void gemm_kernel(
    const float* __restrict__ adj, const uint16_t* __restrict__ zT,
    float* __restrict__ out)
{
    __shared__ float sC[4][16 * 68];   // [wave][row*68 + col], 17.4 KB

    const int blk = blockIdx.x;
    const int rt  = blk & 127;          // 128 row-tiles of 16 rows
    const int b   = blk >> 7;

    const int tid  = threadIdx.x;
    const int w    = tid >> 6;          // wave = adjacency label
    const int lane = tid & 63;
    const int q    = lane >> 4;         // k-quad
    const int mr   = lane & 15;         // row (A) / col (B,C) within 16

    const int n0 = rt * 16;

    const float* aRow =
        adj + ((size_t)(b * 4 + w) * 2048 + (n0 + mr)) * 2048 + q * 8;
    const uint16_t* zCol =
        zT + ((size_t)(b * 4 + w) * 64 + mr) * 2048 + q * 8;

    f32x4 acc[4];
#pragma unroll
    for (int j = 0; j < 4; j++) acc[j] = (f32x4){0.f, 0.f, 0.f, 0.f};

    f32x4  af[2][2];
    short8 bq[2][4];

#define LOADSTEP(pp, s) do {                                                  \
        const float* _a = aRow + (size_t)(s) * 32;                            \
        af[pp][0] = *(const f32x4*)(_a);                                      \
        af[pp][1] = *(const f32x4*)(_a + 4);                                  \
        const uint16_t* _z = zCol + (size_t)(s) * 32;                         \
        bq[pp][0] = *(const short8*)(_z);                                     \
        bq[pp][1] = *(const short8*)(_z + 16 * 2048);                         \
        bq[pp][2] = *(const short8*)(_z + 32 * 2048);                         \
        bq[pp][3] = *(const short8*)(_z + 48 * 2048);                         \
    } while (0)

#define COMPUTE(pp) do {                                                      \
        short8 _fa;                                                           \
        _Pragma("unroll")                                                     \
        for (int j = 0; j < 4; j++) {                                         \
            _fa[j]     = (short)f2bf(af[pp][0][j]);                           \
            _fa[j + 4] = (short)f2bf(af[pp][1][j]);                           \
        }                                                                     \
        _Pragma("unroll")                                                     \
        for (int et = 0; et < 4; et++)                                        \
            acc[et] = __builtin_amdgcn_mfma_f32_16x16x32_bf16(                \
                _fa, bq[pp][et], acc[et], 0, 0, 0);                           \
    } while (0)

    LOADSTEP(0, 0);
    for (int s = 0; s < 62; s += 2) {
        LOADSTEP(1, s + 1);
        COMPUTE(0);
        LOADSTEP(0, s + 2);
        COMPUTE(1);
    }
    LOADSTEP(1, 63);
    COMPUTE(0);
    COMPUTE(1);

#undef LOADSTEP
#undef COMPUTE

    // Stash this wave's C tile: row = q*4 + r, col = et*16 + mr
#pragma unroll
    for (int et = 0; et < 4; et++)
#pragma unroll
        for (int r = 0; r < 4; r++)
            sC[w][(q * 4 + r) * 68 + et * 16 + mr] = acc[et][r];

    __syncthreads();

    // 256 threads reduce 16x64 tile: 4 floats (one float4) each
    {
        const int elem = tid * 4;            // 0..1023
        const int row  = elem >> 6;          // 0..15
        const int col  = elem & 63;          // multiple of 4
        f32x4 s0 = *(const f32x4*)&sC[0][row * 68 + col];
        f32x4 s1 = *(const f32x4*)&sC[1][row * 68 + col];
        f32x4 s2 = *(const f32x4*)&sC[2][row * 68 + col];
        f32x4 s3 = *(const f32x4*)&sC[3][row * 68 + col];
        f32x4 sum = (s0 + s1) + (s2 + s3);
        float* op = out + ((size_t)b * 2048 + n0 + row) * 64 + col;
        f32x4 base = *(const f32x4*)op;
        *(f32x4*)op = base + 0.2f * sum;
    }
}

extern "C" void kernel_launch(void* const* d_in, const int* in_sizes, int n_in,
                              void* d_out, int out_size, void* d_ws, size_t ws_size,
                              hipStream_t stream) {
    const float* x    = (const float*)d_in[0];
    const float* feat = (const float*)d_in[1];
    const float* adj  = (const float*)d_in[2];
    const float* fc_w = (const float*)d_in[3];
    const float* fc_b = (const float*)d_in[4];
    const float* ln_g = (const float*)d_in[5];
    const float* ln_b = (const float*)d_in[6];
    const float* W    = (const float*)d_in[7];
    const float* a    = (const float*)d_in[8];

    float*    out = (float*)d_out;
    uint16_t* zT  = (uint16_t*)d_ws;   // 4*4*64*2048 bf16 = 4 MB

    prep_kernel<<<256, 256, 0, stream>>>(x, feat, fc_w, fc_b, ln_g, ln_b,
                                         W, a, out, zT);
    gemm_kernel<<<512, 256, 0, stream>>>(adj, zT, out);
}

// Round 3
// 456.169 us; speedup vs baseline: 1.0029x; 1.0029x over previous
//
#include <hip/hip_runtime.h>
#include <stdint.h>

// Problem constants (from setup_inputs): B=4, L=4, N=2048, H=64, V=4

typedef __attribute__((ext_vector_type(4))) float  f32x4;
typedef __attribute__((ext_vector_type(8))) short  short8;

static __device__ __forceinline__ uint16_t f2bf(float f) {
    uint32_t u = __float_as_uint(f);
    u += 0x7FFFu + ((u >> 16) & 1u);   // round-to-nearest-even (finite inputs only)
    return (uint16_t)(u >> 16);
}

// ---------------------------------------------------------------------------
// Kernel 1: fused fc + LayerNorm + tanh + projection through M = a@W.
// Writes base = x + 0.2*(h@M0) to d_out (fp32) and zT[b][l][e][m] (bf16,
// B-fragment layout) for l=1..4 to d_ws.
// ---------------------------------------------------------------------------
__global__ __launch_bounds__(256) void prep_kernel(
    const float* __restrict__ x, const float* __restrict__ feat,
    const float* __restrict__ fc_w, const float* __restrict__ fc_b,
    const float* __restrict__ ln_g, const float* __restrict__ ln_b,
    const float* __restrict__ W, const float* __restrict__ a,
    float* __restrict__ out, uint16_t* __restrict__ zT)
{
    __shared__ float    sW[64 * 67];        // fc_w staged, pad 66->67
    __shared__ uint16_t sM[5 * 64 * 64];    // M[l][d][e] in bf16 (40 KB)

    const int tid = threadIdx.x;

    for (int i = tid; i < 64 * 66; i += 256) {
        int d = i / 66, k = i - d * 66;
        sW[d * 67 + k] = fc_w[i];
    }
    for (int i = tid; i < 5 * 64 * 64; i += 256) {
        int l = i >> 12;
        int d = (i >> 6) & 63;
        int e = i & 63;
        const float* wp = W + (size_t)(d * 4) * 64 + e;
        float acc = a[l * 4 + 0] * wp[0]   + a[l * 4 + 1] * wp[64]
                  + a[l * 4 + 2] * wp[128] + a[l * 4 + 3] * wp[192];
        sM[i] = f2bf(acc);
    }
    __syncthreads();

    const int wave = tid >> 6, lane = tid & 63;
    const int row0 = blockIdx.x * 32 + wave * 8;   // global row in [0, 8192)
    const int b    = row0 >> 11;
    const int m0   = row0 & 2047;

    const float fcb = fc_b[lane], lng = ln_g[lane], lnb = ln_b[lane];

    float xv[8], hv[8];
#pragma unroll
    for (int r = 0; r < 8; r++) {
        const int row = row0 + r;
        xv[r] = x[(size_t)row * 64 + lane];
        const float f0 = feat[row * 2 + 0];
        const float f1 = feat[row * 2 + 1];
        float acc = fcb;
#pragma unroll
        for (int k = 0; k < 64; k++)
            acc += __shfl(xv[r], k) * sW[lane * 67 + k];
        acc += f0 * sW[lane * 67 + 64] + f1 * sW[lane * 67 + 65];
        float s = acc, s2 = acc * acc;
#pragma unroll
        for (int off = 32; off > 0; off >>= 1) {
            s  += __shfl_xor(s,  off);
            s2 += __shfl_xor(s2, off);
        }
        const float mean = s * (1.0f / 64.0f);
        const float var  = s2 * (1.0f / 64.0f) - mean * mean;
        const float y = (acc - mean) * rsqrtf(var + 1e-5f) * lng + lnb;
        hv[r] = tanhf(y);
    }

    float accz[5][8];
#pragma unroll
    for (int l = 0; l < 5; l++)
#pragma unroll
        for (int r = 0; r < 8; r++) accz[l][r] = 0.0f;

    for (int d = 0; d < 64; d++) {
        float hb[8];
#pragma unroll
        for (int r = 0; r < 8; r++) hb[r] = __shfl(hv[r], d);
#pragma unroll
        for (int l = 0; l < 5; l++) {
            const float mv =
                __uint_as_float(((uint32_t)sM[(l << 12) + (d << 6) + lane]) << 16);
#pragma unroll
            for (int r = 0; r < 8; r++) accz[l][r] += hb[r] * mv;
        }
    }

#pragma unroll
    for (int r = 0; r < 8; r++)
        out[(size_t)(row0 + r) * 64 + lane] = xv[r] + 0.2f * accz[0][r];

#pragma unroll
    for (int l = 1; l < 5; l++) {
        uint32_t w0 = (uint32_t)f2bf(accz[l][0]) | ((uint32_t)f2bf(accz[l][1]) << 16);
        uint32_t w1 = (uint32_t)f2bf(accz[l][2]) | ((uint32_t)f2bf(accz[l][3]) << 16);
        uint32_t w2 = (uint32_t)f2bf(accz[l][4]) | ((uint32_t)f2bf(accz[l][5]) << 16);
        uint32_t w3 = (uint32_t)f2bf(accz[l][6]) | ((uint32_t)f2bf(accz[l][7]) << 16);
        uint4* dst = (uint4*)(zT + (((size_t)(b * 4 + (l - 1)) * 64 + lane) * 2048 + m0));
        *dst = make_uint4(w0, w1, w2, w3);
    }
}

// ---------------------------------------------------------------------------
// Kernel 2: out[b,n,e] = base[b,n,e] + 0.2 * sum_l sum_m adj[b,l,n,m]*z[l][m][e]
// One block (4 waves) owns a (b, 16-row) tile. Wave w handles label l=w over
// the FULL K=2048 with a 4-deep register pipeline (24 loads in flight/wave),
// then a 4-way LDS reduction and a single float4 RMW store. Zero atomics.
// Grid: 4(b) * 128(row-tile) = 512 blocks x 256 threads.
// ---------------------------------------------------------------------------
__global__ __launch_bounds__(256) void gemm_kernel(
    const float* __restrict__ adj, const uint16_t* __restrict__ zT,
    float* __restrict__ out)
{
    __shared__ float sC[4][16 * 68];   // [wave][row*68 + col], 17.4 KB

    const int blk = blockIdx.x;
    const int rt  = blk & 127;          // 128 row-tiles of 16 rows
    const int b   = blk >> 7;

    const int tid  = threadIdx.x;
    const int w    = tid >> 6;          // wave = adjacency label
    const int lane = tid & 63;
    const int q    = lane >> 4;         // k-quad
    const int mr   = lane & 15;         // row (A) / col (B,C) within 16

    const int n0 = rt * 16;

    const float* aRow =
        adj + ((size_t)(b * 4 + w) * 2048 + (n0 + mr)) * 2048 + q * 8;
    const uint16_t* zCol =
        zT + ((size_t)(b * 4 + w) * 64 + mr) * 2048 + q * 8;

    f32x4 acc[4];
#pragma unroll
    for (int j = 0; j < 4; j++) acc[j] = (f32x4){0.f, 0.f, 0.f, 0.f};

    f32x4  af[4][2];    // [buf][half]     — 4-deep pipeline
    short8 bq[4][4];    // [buf][e-tile]

#define LOADSTEP(pp, s) do {                                                  \
        const float* _a = aRow + (size_t)(s) * 32;                            \
        af[pp][0] = *(const f32x4*)(_a);                                      \
        af[pp][1] = *(const f32x4*)(_a + 4);                                  \
        const uint16_t* _z = zCol + (size_t)(s) * 32;                         \
        bq[pp][0] = *(const short8*)(_z);                                     \
        bq[pp][1] = *(const short8*)(_z + 16 * 2048);                         \
        bq[pp][2] = *(const short8*)(_z + 32 * 2048);                         \
        bq[pp][3] = *(const short8*)(_z + 48 * 2048);                         \
    } while (0)

#define COMPUTE(pp) do {                                                      \
        short8 _fa;                                                           \
        _Pragma("unroll")                                                     \
        for (int j = 0; j < 4; j++) {                                         \
            _fa[j]     = (short)f2bf(af[pp][0][j]);                           \
            _fa[j + 4] = (short)f2bf(af[pp][1][j]);                           \
        }                                                                     \
        _Pragma("unroll")                                                     \
        for (int et = 0; et < 4; et++)                                        \
            acc[et] = __builtin_amdgcn_mfma_f32_16x16x32_bf16(                \
                _fa, bq[pp][et], acc[et], 0, 0, 0);                           \
    } while (0)

    LOADSTEP(0, 0);
    LOADSTEP(1, 1);
    LOADSTEP(2, 2);
    // invariant at loop top: buf0=s, buf1=s+1, buf2=s+2 loaded
    for (int s = 0; s < 60; s += 4) {
        LOADSTEP(3, s + 3); COMPUTE(0);
        LOADSTEP(0, s + 4); COMPUTE(1);
        LOADSTEP(1, s + 5); COMPUTE(2);
        LOADSTEP(2, s + 6); COMPUTE(3);
    }
    // after loop: computed through step 59; buf0=60, buf1=61, buf2=62
    LOADSTEP(3, 63);
    COMPUTE(0);
    COMPUTE(1);
    COMPUTE(2);
    COMPUTE(3);

#undef LOADSTEP
#undef COMPUTE

    // Stash this wave's C tile: row = q*4 + r, col = et*16 + mr
#pragma unroll
    for (int et = 0; et < 4; et++)
#pragma unroll
        for (int r = 0; r < 4; r++)
            sC[w][(q * 4 + r) * 68 + et * 16 + mr] = acc[et][r];

    __syncthreads();

    // 256 threads reduce 16x64 tile: 4 floats (one float4) each
    {
        const int elem = tid * 4;            // 0..1023
        const int row  = elem >> 6;          // 0..15
        const int col  = elem & 63;          // multiple of 4
        f32x4 s0 = *(const f32x4*)&sC[0][row * 68 + col];
        f32x4 s1 = *(const f32x4*)&sC[1][row * 68 + col];
        f32x4 s2 = *(const f32x4*)&sC[2][row * 68 + col];
        f32x4 s3 = *(const f32x4*)&sC[3][row * 68 + col];
        f32x4 sum = (s0 + s1) + (s2 + s3);
        float* op = out + ((size_t)b * 2048 + n0 + row) * 64 + col;
        f32x4 base = *(const f32x4*)op;
        *(f32x4*)op = base + 0.2f * sum;
    }
}

extern "C" void kernel_launch(void* const* d_in, const int* in_sizes, int n_in,
                              void* d_out, int out_size, void* d_ws, size_t ws_size,
                              hipStream_t stream) {
    const float* x    = (const float*)d_in[0];
    const float* feat = (const float*)d_in[1];
    const float* adj  = (const float*)d_in[2];
    const float* fc_w = (const float*)d_in[3];
    const float* fc_b = (const float*)d_in[4];
    const float* ln_g = (const float*)d_in[5];
    const float* ln_b = (const float*)d_in[6];
    const float* W    = (const float*)d_in[7];
    const float* a    = (const float*)d_in[8];

    float*    out = (float*)d_out;
    uint16_t* zT  = (uint16_t*)d_ws;   // 4*4*64*2048 bf16 = 4 MB

    prep_kernel<<<256, 256, 0, stream>>>(x, feat, fc_w, fc_b, ln_g, ln_b,
                                         W, a, out, zT);
    gemm_kernel<<<512, 256, 0, stream>>>(adj, zT, out);
}